// Round 2
// baseline (246.362 us; speedup 1.0000x reference)
//
#include <hip/hip_runtime.h>

// KNRM round 12: coalesced LDS-staged d-row gather.
//  R11 post-mortem: fp8 halved bytes/lines but gave only -6.4us -> main is
//  bound by SCATTERED REQUEST RATE, not line rate (request count was
//  unchanged: 40x8B scattered loads/row, lanes 0-15 = 16 different rows).
//  R12: stage each step's 128 d-rows into LDS with coalesced copies
//  (16 consecutive threads x uint4 per contiguous 320B row = 5x64B
//  requests/row, 8x fewer than before), double-buffered (T14: global loads
//  issued before MFMA, ds_write after exp tail). Rows stored PERMUTED
//  (done free in norm): element e=ks*32+q*8+r -> byte q*80+ks*8+r, so
//  fragment reads are ds_read_b128 (2 ks-steps per read). Stride 336B ->
//  start-slot (5r+5q+ks2) mod 8 perfectly uniform across the wave.
//  Per-lane fragment contents identical to R11 (passed) - layout-only.

#define B      256
#define BQ     32
#define BD     512
#define EDIM   300
#define ROWB   320   // bytes per fp8 row (300 data + 20 zero pad)
#define NK     11
#define DSTR   336   // LDS row stride (bytes): 336/16=21 odd -> uniform b128 slots

typedef float floatx4 __attribute__((ext_vector_type(4)));
typedef long  longx2  __attribute__((ext_vector_type(2)));

__device__ __forceinline__ float sbc(float x) {   // force into SGPR
    return __uint_as_float(__builtin_amdgcn_readfirstlane(__float_as_uint(x)));
}

// ---------------- Phase 0: mark referenced vocab rows ----------------
__global__ __launch_bounds__(256)
void knrm_mark(const int* __restrict__ qtok, const int* __restrict__ dtok,
               unsigned char* __restrict__ flags)
{
    int i = blockIdx.x * 256 + threadIdx.x;
    const int NQ = B * BQ;              // 8192
    const int ND = B * BD;              // 131072
    if (i < NQ) flags[qtok[i]] = 1;
    else if (i < NQ + ND) flags[dtok[i - NQ]] = 1;
}

// ---------------- Phase 1: normalize / quantize referenced rows ----------------
// 8 lanes/row, 32 rows per 256-thread block. Per-row dynamic scale
// (max|x| -> 64), rnorm from the DEQUANTIZED values. Output rows stored in
// the PERMUTED layout: element e = ks*32 + q*8 + r  ->  byte q*80 + ks*8 + r.
// Group j (elements 8j..8j+7) has fixed (ks=j>>2, q=j&3) -> one contiguous
// 8-B destination at uint2 index (j&3)*10 + (j>>2).
__global__ __launch_bounds__(256)
void knrm_norm(const float* __restrict__ emb, const unsigned char* __restrict__ flags,
               unsigned char* __restrict__ ebf, float* __restrict__ rnorm, int V)
{
    int r    = blockIdx.x * 32 + (threadIdx.x >> 3);
    int part = threadIdx.x & 7;
    if (r >= V) return;
    if (!flags[r]) return;              // unreferenced: never read by main
    const float4* src = (const float4*)(emb + (size_t)r * EDIM);
    float v[5][8];
    float mx = 0.f;
    #pragma unroll
    for (int i = 0; i < 5; ++i) {
        int j = part + i * 8;               // 8-float group index 0..39
        #pragma unroll
        for (int t = 0; t < 8; ++t) v[i][t] = 0.f;
        if (j < 37) {
            float4 a = src[2 * j];
            float4 c = src[2 * j + 1];
            v[i][0] = a.x; v[i][1] = a.y; v[i][2] = a.z; v[i][3] = a.w;
            v[i][4] = c.x; v[i][5] = c.y; v[i][6] = c.z; v[i][7] = c.w;
        } else if (j == 37) {               // floats 296..299 valid, 300..303 pad
            float4 a = src[74];
            v[i][0] = a.x; v[i][1] = a.y; v[i][2] = a.z; v[i][3] = a.w;
        }                                   // j = 38,39: all pad zeros
        #pragma unroll
        for (int t = 0; t < 8; ++t) mx = fmaxf(mx, fabsf(v[i][t]));
    }
    mx = fmaxf(mx, __shfl_xor(mx, 1));
    mx = fmaxf(mx, __shfl_xor(mx, 2));
    mx = fmaxf(mx, __shfl_xor(mx, 4));
    float s = (mx > 0.f) ? (64.f / mx) : 0.f;   // max -> 64: e4m3 sweet spot

    float ss = 0.f;
    uint2* dst = (uint2*)(ebf + (size_t)r * ROWB);   // 40 x uint2 per row
    #pragma unroll
    for (int i = 0; i < 5; ++i) {
        int j = part + i * 8;
        unsigned int w0 = 0u, w1 = 0u;
        w0 = __builtin_amdgcn_cvt_pk_fp8_f32(v[i][0] * s, v[i][1] * s, w0, false);
        w0 = __builtin_amdgcn_cvt_pk_fp8_f32(v[i][2] * s, v[i][3] * s, w0, true);
        w1 = __builtin_amdgcn_cvt_pk_fp8_f32(v[i][4] * s, v[i][5] * s, w1, false);
        w1 = __builtin_amdgcn_cvt_pk_fp8_f32(v[i][6] * s, v[i][7] * s, w1, true);
        float g;
        g = __builtin_amdgcn_cvt_f32_fp8(w0, 0); ss += g * g;
        g = __builtin_amdgcn_cvt_f32_fp8(w0, 1); ss += g * g;
        g = __builtin_amdgcn_cvt_f32_fp8(w0, 2); ss += g * g;
        g = __builtin_amdgcn_cvt_f32_fp8(w0, 3); ss += g * g;
        g = __builtin_amdgcn_cvt_f32_fp8(w1, 0); ss += g * g;
        g = __builtin_amdgcn_cvt_f32_fp8(w1, 1); ss += g * g;
        g = __builtin_amdgcn_cvt_f32_fp8(w1, 2); ss += g * g;
        g = __builtin_amdgcn_cvt_f32_fp8(w1, 3); ss += g * g;
        uint2 o; o.x = w0; o.y = w1;
        dst[(j & 3) * 10 + (j >> 2)] = o;   // permuted: byte q*80 + ks*8
    }
    ss += __shfl_xor(ss, 1);
    ss += __shfl_xor(ss, 2);
    ss += __shfl_xor(ss, 4);
    if (part == 0) rnorm[r] = 1.f / (sqrtf(ss) + 1e-13f);
}

// ---------------- Phase 2: fused gather + fp8 MFMA + Gaussians + epilogue ----------------
// Coalesced staging of one step's 128 d-rows: 16 consecutive threads per row,
// uint4 chunks of the contiguous 320-B row (uint4 part, plus 16+part for part<4).
__device__ __forceinline__ void stage_ld(uint4 t0[4], uint4 t1[4],
        const unsigned char* __restrict__ ebf, const int* __restrict__ dtok_blk,
        int s, int tid)
{
    int part = tid & 15, rr = tid >> 4;      // rr in 0..31
    #pragma unroll
    for (int p = 0; p < 4; ++p) {
        int i = p * 32 + rr;                 // row 0..127 within the step
        int tok = dtok_blk[s * 128 + i];     // 16-thread broadcast load
        const uint4* src = (const uint4*)(ebf + (size_t)tok * ROWB);
        t0[p] = src[part];
        if (part < 4) t1[p] = src[16 + part];
    }
}
__device__ __forceinline__ void stage_st(const uint4 t0[4], const uint4 t1[4],
        unsigned char* dst_base, int tid)
{
    int part = tid & 15, rr = tid >> 4;
    #pragma unroll
    for (int p = 0; p < 4; ++p) {
        int i = p * 32 + rr;
        uint4* dst = (uint4*)(dst_base + i * DSTR);
        dst[part] = t0[p];
        if (part < 4) dst[16 + part] = t1[p];
    }
}

__global__ __launch_bounds__(512, 2)
void knrm_main9(const int* __restrict__ qtok, const int* __restrict__ dtok,
                const unsigned char* __restrict__ ebf, const float* __restrict__ rnorm,
                const float* __restrict__ mu, const float* __restrict__ sigma,
                const float* __restrict__ dw, const float* __restrict__ db,
                float* __restrict__ out)
{
    __shared__ __align__(16) unsigned char q_buf[BQ * DSTR];       // 10752 B
    __shared__ __align__(16) unsigned char d_buf[2][128 * DSTR];   // 86016 B
    __shared__ float pkq_s[BQ * NK];
    __shared__ float rqs[BQ];
    __shared__ float red[BQ];

    const int tid  = threadIdx.x;
    const int lane = tid & 63;
    const int wv   = tid >> 6;            // 0..7
    const int b    = blockIdx.x;          // one block per batch
    const int l16  = lane & 15;
    const int quad = lane >> 4;
    const int* dtok_blk = dtok + b * BD;

    for (int i = tid; i < BQ * NK; i += 512) pkq_s[i] = 0.f;
    if (tid < BQ) rqs[tid] = rnorm[qtok[b * BQ + tid]];

    // this wave's d rows: step s -> row s*128 + wv*16 + l16
    const int dbase = b * BD + wv * 16 + l16;
    int   td[4];
    float rd[4], dm[4];
    #pragma unroll
    for (int s = 0; s < 4; ++s) {
        td[s] = dtok[dbase + s * 128];
        rd[s] = rnorm[td[s]];
        dm[s] = (td[s] > 0) ? 1.f : 0.f;
    }

    // stage step-0 d tile + the 32 q rows (all writes land before the s=0 barrier)
    uint4 ta[4], tb[4];
    stage_ld(ta, tb, ebf, dtok_blk, 0, tid);
    {
        int row = tid >> 4, part = tid & 15;
        int tokq = qtok[b * BQ + row];
        const uint4* src  = (const uint4*)(ebf + (size_t)tokq * ROWB);
        uint4*       qrow = (uint4*)&q_buf[row * DSTR];
        qrow[part] = src[part];
        if (part < 4) qrow[16 + part] = src[16 + part];
    }
    stage_st(ta, tb, d_buf[0], tid);

    float mur[NK], cfr[NK];
    #pragma unroll
    for (int k = 0; k < NK; ++k) {
        float s = sbc(sigma[k]);
        mur[k] = sbc(mu[k]);
        cfr[k] = -0.5f / (s * s);
    }

    float pk[2][4][NK];
    #pragma unroll
    for (int slab = 0; slab < 2; ++slab)
        #pragma unroll
        for (int r = 0; r < 4; ++r)
            #pragma unroll
            for (int k = 0; k < NK; ++k) pk[slab][r][k] = 0.f;

    const unsigned char* a0 = &q_buf[l16 * DSTR + quad * 80];
    const unsigned char* a1 = a0 + 16 * DSTR;

    int cur = 0;
    float rqv[8];

    #pragma unroll
    for (int s = 0; s < 4; ++s) {
        __syncthreads();                 // d_buf[cur] ready; d_buf[cur^1] free

        // issue next step's global loads first (land under MFMA + exp tail)
        if (s < 3) stage_ld(ta, tb, ebf, dtok_blk, s + 1, tid);
        if (s == 0) {                    // rqs ready only after the first barrier
            #pragma unroll
            for (int slab = 0; slab < 2; ++slab)
                #pragma unroll
                for (int r = 0; r < 4; ++r)
                    rqv[slab * 4 + r] = rqs[slab * 16 + quad * 4 + r];
        }

        const unsigned char* bp = d_buf[cur] + (wv * 16 + l16) * DSTR + quad * 80;
        floatx4 acc0 = {0.f, 0.f, 0.f, 0.f};
        floatx4 acc1 = {0.f, 0.f, 0.f, 0.f};
        #pragma unroll
        for (int k2 = 0; k2 < 5; ++k2) {
            longx2 vA0 = *(const longx2*)(a0 + k2 * 16);
            longx2 vA1 = *(const longx2*)(a1 + k2 * 16);
            longx2 vB  = *(const longx2*)(bp + k2 * 16);
            acc0 = __builtin_amdgcn_mfma_f32_16x16x32_fp8_fp8(vA0.x, vB.x, acc0, 0, 0, 0);
            acc0 = __builtin_amdgcn_mfma_f32_16x16x32_fp8_fp8(vA0.y, vB.y, acc0, 0, 0, 0);
            acc1 = __builtin_amdgcn_mfma_f32_16x16x32_fp8_fp8(vA1.x, vB.x, acc1, 0, 0, 0);
            acc1 = __builtin_amdgcn_mfma_f32_16x16x32_fp8_fp8(vA1.y, vB.y, acc1, 0, 0, 0);
        }

        // exp tail (global loads still in flight underneath)
        #pragma unroll
        for (int slab = 0; slab < 2; ++slab) {
            floatx4 acc = slab ? acc1 : acc0;
            #pragma unroll
            for (int r = 0; r < 4; ++r) {
                float c0 = acc[r] * rqv[slab * 4 + r] * rd[s];
                #pragma unroll
                for (int k = 0; k < NK; ++k) {
                    float d0 = c0 - mur[k];
                    pk[slab][r][k] += dm[s] * __expf(cfr[k] * d0 * d0);
                }
            }
        }

        // write next tile late (vmcnt wait mostly drained by now)
        if (s < 3) stage_st(ta, tb, d_buf[cur ^ 1], tid);
        cur ^= 1;
    }

    // ONE cross-lane reduce (sum 16 d-lanes per quad) + LDS combine
    #pragma unroll
    for (int slab = 0; slab < 2; ++slab)
        #pragma unroll
        for (int r = 0; r < 4; ++r)
            #pragma unroll
            for (int k = 0; k < NK; ++k) {
                float v = pk[slab][r][k];
                v += __shfl_xor(v, 1);
                v += __shfl_xor(v, 2);
                v += __shfl_xor(v, 4);
                v += __shfl_xor(v, 8);
                if (l16 == 0)
                    atomicAdd(&pkq_s[(slab * 16 + quad * 4 + r) * NK + k], v);
            }
    __syncthreads();

    // fused epilogue: log/mask/dot -> out[b]
    if (tid < BQ) {
        int tok = qtok[b * BQ + tid];
        float sq = 0.f;
        if (tok > 0) {
            #pragma unroll
            for (int k = 0; k < NK; ++k) {
                float s = fmaxf(pkq_s[tid * NK + k], 1e-10f);
                sq += __logf(s) * 0.01f * dw[k];
            }
        }
        red[tid] = sq;
    }
    __syncthreads();
    if (tid == 0) {
        float s = db[0];
        #pragma unroll 8
        for (int i = 0; i < BQ; ++i) s += red[i];
        out[b] = s;
    }
}

extern "C" void kernel_launch(void* const* d_in, const int* in_sizes, int n_in,
                              void* d_out, int out_size, void* d_ws, size_t ws_size,
                              hipStream_t stream)
{
    const int*   qtok  = (const int*)d_in[0];
    const int*   dtok  = (const int*)d_in[1];
    const float* emb   = (const float*)d_in[2];
    const float* dw    = (const float*)d_in[3];
    const float* dbias = (const float*)d_in[4];
    const float* mu    = (const float*)d_in[5];
    const float* sg    = (const float*)d_in[6];
    float* out = (float*)d_out;

    const int V = in_sizes[2] / EDIM;   // 100000
    const size_t ebf_bytes = (size_t)V * ROWB;       // 32 MB
    const size_t rn_bytes  = (size_t)((V * 4 + 255) & ~255);

    unsigned char* ebf   = (unsigned char*)d_ws;
    float*         rnorm = (float*)((char*)d_ws + ebf_bytes);
    unsigned char* flags = (unsigned char*)((char*)d_ws + ebf_bytes + rn_bytes);

    hipMemsetAsync(flags, 0, V, stream);
    const int ntok = B * BQ + B * BD;   // 139264
    knrm_mark<<<(ntok + 255) / 256, 256, 0, stream>>>(qtok, dtok, flags);
    knrm_norm<<<(V + 31) / 32, 256, 0, stream>>>(emb, flags, ebf, rnorm, V);
    knrm_main9<<<B, 512, 0, stream>>>(qtok, dtok, ebf, rnorm, mu, sg, dw, dbias, out);
}

// Round 3
// 225.168 us; speedup vs baseline: 1.0941x; 1.0941x over previous
//
#include <hip/hip_runtime.h>

// KNRM round 13: R11 revert + prefetch-ALL-steps B-fragments.
//  R12 post-mortem: LDS staging died of register spills (VGPR_Count=88,
//  WRITE_SIZE=48MB of scratch, VALUBusy 0.44%) - coalescing never tested.
//  R13 theory: main8 is LATENCY-SERIALIZATION bound: 1 block/CU (grid=256),
//  8 waves/CU fixed, and each of the 4 steps exposes an un-hidden gather
//  latency slice (exp tail ~1us < gather latency). Registers are the only
//  slack resource -> prefetch all 4 steps' fragments (long bf[4][10], 80
//  VGPR, statically indexed) BEFORE the barrier, so all ~40 scattered b64
//  loads/lane are in flight under q-staging + barrier + setup, and latency
//  is exposed ONCE. Everything else identical to R11 (passed, 223.5us):
//  fp8 e4m3 rows with per-row scale (max->64), rnorm from dequantized
//  values (exact-match cosine==1), linear row layout, 320B rows.

#define B      256
#define BQ     32
#define BD     512
#define EDIM   300
#define ROWB   320   // bytes per fp8 row (300 data + 20 zero pad)
#define NK     11
#define QSTR   336   // q_buf row stride in BYTES: 16B-aligned, /4 == 84 = 20 mod 32

typedef float floatx4 __attribute__((ext_vector_type(4)));

__device__ __forceinline__ float sbc(float x) {   // force into SGPR
    return __uint_as_float(__builtin_amdgcn_readfirstlane(__float_as_uint(x)));
}

// ---------------- Phase 0: mark referenced vocab rows ----------------
__global__ __launch_bounds__(256)
void knrm_mark(const int* __restrict__ qtok, const int* __restrict__ dtok,
               unsigned char* __restrict__ flags)
{
    int i = blockIdx.x * 256 + threadIdx.x;
    const int NQ = B * BQ;              // 8192
    const int ND = B * BD;              // 131072
    if (i < NQ) flags[qtok[i]] = 1;
    else if (i < NQ + ND) flags[dtok[i - NQ]] = 1;
}

// ---------------- Phase 1: normalize / quantize referenced rows ----------------
// 8 lanes/row, 32 rows per 256-thread block. Per-row dynamic scale
// (max|x| -> 64), rnorm from the DEQUANTIZED values, linear row layout.
__global__ __launch_bounds__(256)
void knrm_norm(const float* __restrict__ emb, const unsigned char* __restrict__ flags,
               unsigned char* __restrict__ ebf, float* __restrict__ rnorm, int V)
{
    int r    = blockIdx.x * 32 + (threadIdx.x >> 3);
    int part = threadIdx.x & 7;
    if (r >= V) return;
    if (!flags[r]) return;              // unreferenced: never read by main
    const float4* src = (const float4*)(emb + (size_t)r * EDIM);
    float v[5][8];
    float mx = 0.f;
    #pragma unroll
    for (int i = 0; i < 5; ++i) {
        int j = part + i * 8;               // 8-float group index 0..39
        #pragma unroll
        for (int t = 0; t < 8; ++t) v[i][t] = 0.f;
        if (j < 37) {
            float4 a = src[2 * j];
            float4 c = src[2 * j + 1];
            v[i][0] = a.x; v[i][1] = a.y; v[i][2] = a.z; v[i][3] = a.w;
            v[i][4] = c.x; v[i][5] = c.y; v[i][6] = c.z; v[i][7] = c.w;
        } else if (j == 37) {               // floats 296..299 valid, 300..303 pad
            float4 a = src[74];
            v[i][0] = a.x; v[i][1] = a.y; v[i][2] = a.z; v[i][3] = a.w;
        }                                   // j = 38,39: all pad zeros
        #pragma unroll
        for (int t = 0; t < 8; ++t) mx = fmaxf(mx, fabsf(v[i][t]));
    }
    mx = fmaxf(mx, __shfl_xor(mx, 1));
    mx = fmaxf(mx, __shfl_xor(mx, 2));
    mx = fmaxf(mx, __shfl_xor(mx, 4));
    float s = (mx > 0.f) ? (64.f / mx) : 0.f;   // max -> 64: e4m3 sweet spot

    float ss = 0.f;
    uint2* dst = (uint2*)(ebf + (size_t)r * ROWB);   // 40 x uint2 per row
    #pragma unroll
    for (int i = 0; i < 5; ++i) {
        int j = part + i * 8;
        unsigned int w0 = 0u, w1 = 0u;
        w0 = __builtin_amdgcn_cvt_pk_fp8_f32(v[i][0] * s, v[i][1] * s, w0, false);
        w0 = __builtin_amdgcn_cvt_pk_fp8_f32(v[i][2] * s, v[i][3] * s, w0, true);
        w1 = __builtin_amdgcn_cvt_pk_fp8_f32(v[i][4] * s, v[i][5] * s, w1, false);
        w1 = __builtin_amdgcn_cvt_pk_fp8_f32(v[i][6] * s, v[i][7] * s, w1, true);
        float g;
        g = __builtin_amdgcn_cvt_f32_fp8(w0, 0); ss += g * g;
        g = __builtin_amdgcn_cvt_f32_fp8(w0, 1); ss += g * g;
        g = __builtin_amdgcn_cvt_f32_fp8(w0, 2); ss += g * g;
        g = __builtin_amdgcn_cvt_f32_fp8(w0, 3); ss += g * g;
        g = __builtin_amdgcn_cvt_f32_fp8(w1, 0); ss += g * g;
        g = __builtin_amdgcn_cvt_f32_fp8(w1, 1); ss += g * g;
        g = __builtin_amdgcn_cvt_f32_fp8(w1, 2); ss += g * g;
        g = __builtin_amdgcn_cvt_f32_fp8(w1, 3); ss += g * g;
        uint2 o; o.x = w0; o.y = w1;
        dst[j] = o;
    }
    ss += __shfl_xor(ss, 1);
    ss += __shfl_xor(ss, 2);
    ss += __shfl_xor(ss, 4);
    if (part == 0) rnorm[r] = 1.f / (sqrtf(ss) + 1e-13f);
}

// ---------------- Phase 2: fused gather + fp8 MFMA + Gaussians + epilogue ----------------
__device__ __forceinline__ void load_frags(long* bf, const unsigned char* __restrict__ ebf,
                                           int tok, int quad)
{
    const long* src = (const long*)(ebf + (size_t)tok * ROWB);   // 40 longs/row
    #pragma unroll
    for (int ks = 0; ks < 10; ++ks)
        bf[ks] = src[quad + ks * 4];
}

__global__ __launch_bounds__(512, 2)
void knrm_main10(const int* __restrict__ qtok, const int* __restrict__ dtok,
                 const unsigned char* __restrict__ ebf, const float* __restrict__ rnorm,
                 const float* __restrict__ mu, const float* __restrict__ sigma,
                 const float* __restrict__ dw, const float* __restrict__ db,
                 float* __restrict__ out)
{
    __shared__ __align__(16) unsigned char q_buf[BQ * QSTR];   // 10752 B
    __shared__ float pkq_s[BQ * NK];
    __shared__ float rqs[BQ];
    __shared__ float red[BQ];

    const int tid  = threadIdx.x;
    const int lane = tid & 63;
    const int wv   = tid >> 6;            // 0..7
    const int b    = blockIdx.x;          // one block per batch
    const int l16  = lane & 15;
    const int quad = lane >> 4;

    for (int i = tid; i < BQ * NK; i += 512) pkq_s[i] = 0.f;
    if (tid < BQ) rqs[tid] = rnorm[qtok[b * BQ + tid]];

    // this wave's d rows: step s -> row s*128 + wv*16 + l16
    const int dbase = b * BD + wv * 16 + l16;
    int   td[4];
    float rd[4], dm[4];
    #pragma unroll
    for (int s = 0; s < 4; ++s) {
        td[s] = dtok[dbase + s * 128];
        rd[s] = rnorm[td[s]];
        dm[s] = (td[s] > 0) ? 1.f : 0.f;
    }

    // stage the 32 q rows once per batch: 16 threads/row, uint4 chunks (20/row)
    {
        int row = tid >> 4, part = tid & 15;
        int tok = qtok[b * BQ + row];
        const uint4* src  = (const uint4*)(ebf + (size_t)tok * ROWB);
        uint4*       qrow = (uint4*)&q_buf[row * QSTR];
        qrow[part] = src[part];
        if (part < 4) qrow[16 + part] = src[16 + part];
    }

    // prefetch ALL FOUR steps' B-fragments: ~40 scattered b64 loads in
    // flight at once; latency exposed once, under staging + barrier + setup.
    long bf[4][10];
    #pragma unroll
    for (int s = 0; s < 4; ++s)
        load_frags(bf[s], ebf, td[s], quad);

    __syncthreads();

    float mur[NK], cfr[NK];
    #pragma unroll
    for (int k = 0; k < NK; ++k) {
        float s = sbc(sigma[k]);
        mur[k] = sbc(mu[k]);
        cfr[k] = -0.5f / (s * s);
    }
    float rqv[8];
    #pragma unroll
    for (int slab = 0; slab < 2; ++slab)
        #pragma unroll
        for (int r = 0; r < 4; ++r)
            rqv[slab * 4 + r] = rqs[slab * 16 + quad * 4 + r];

    const unsigned char* a0 = &q_buf[l16 * QSTR + quad * 8];
    const unsigned char* a1 = a0 + 16 * QSTR;

    float pk[2][4][NK];
    #pragma unroll
    for (int slab = 0; slab < 2; ++slab)
        #pragma unroll
        for (int r = 0; r < 4; ++r)
            #pragma unroll
            for (int k = 0; k < NK; ++k) pk[slab][r][k] = 0.f;

    #pragma unroll
    for (int s = 0; s < 4; ++s) {
        floatx4 acc0 = {0.f, 0.f, 0.f, 0.f};
        floatx4 acc1 = {0.f, 0.f, 0.f, 0.f};
        #pragma unroll
        for (int ks = 0; ks < 10; ++ks) {
            long aA = *(const long*)(a0 + ks * 32);
            long aB = *(const long*)(a1 + ks * 32);
            acc0 = __builtin_amdgcn_mfma_f32_16x16x32_fp8_fp8(aA, bf[s][ks], acc0, 0, 0, 0);
            acc1 = __builtin_amdgcn_mfma_f32_16x16x32_fp8_fp8(aB, bf[s][ks], acc1, 0, 0, 0);
        }

        #pragma unroll
        for (int slab = 0; slab < 2; ++slab) {
            floatx4 acc = slab ? acc1 : acc0;
            #pragma unroll
            for (int r = 0; r < 4; ++r) {
                float c0 = acc[r] * rqv[slab * 4 + r] * rd[s];
                #pragma unroll
                for (int k = 0; k < NK; ++k) {
                    float d0 = c0 - mur[k];
                    pk[slab][r][k] += dm[s] * __expf(cfr[k] * d0 * d0);
                }
            }
        }
    }

    // ONE cross-lane reduce (sum 16 d-lanes per quad) + LDS combine
    #pragma unroll
    for (int slab = 0; slab < 2; ++slab)
        #pragma unroll
        for (int r = 0; r < 4; ++r)
            #pragma unroll
            for (int k = 0; k < NK; ++k) {
                float v = pk[slab][r][k];
                v += __shfl_xor(v, 1);
                v += __shfl_xor(v, 2);
                v += __shfl_xor(v, 4);
                v += __shfl_xor(v, 8);
                if (l16 == 0)
                    atomicAdd(&pkq_s[(slab * 16 + quad * 4 + r) * NK + k], v);
            }
    __syncthreads();

    // fused epilogue: log/mask/dot -> out[b]
    if (tid < BQ) {
        int tok = qtok[b * BQ + tid];
        float sq = 0.f;
        if (tok > 0) {
            #pragma unroll
            for (int k = 0; k < NK; ++k) {
                float s = fmaxf(pkq_s[tid * NK + k], 1e-10f);
                sq += __logf(s) * 0.01f * dw[k];
            }
        }
        red[tid] = sq;
    }
    __syncthreads();
    if (tid == 0) {
        float s = db[0];
        #pragma unroll 8
        for (int i = 0; i < BQ; ++i) s += red[i];
        out[b] = s;
    }
}

extern "C" void kernel_launch(void* const* d_in, const int* in_sizes, int n_in,
                              void* d_out, int out_size, void* d_ws, size_t ws_size,
                              hipStream_t stream)
{
    const int*   qtok  = (const int*)d_in[0];
    const int*   dtok  = (const int*)d_in[1];
    const float* emb   = (const float*)d_in[2];
    const float* dw    = (const float*)d_in[3];
    const float* dbias = (const float*)d_in[4];
    const float* mu    = (const float*)d_in[5];
    const float* sg    = (const float*)d_in[6];
    float* out = (float*)d_out;

    const int V = in_sizes[2] / EDIM;   // 100000
    const size_t ebf_bytes = (size_t)V * ROWB;       // 32 MB
    const size_t rn_bytes  = (size_t)((V * 4 + 255) & ~255);

    unsigned char* ebf   = (unsigned char*)d_ws;
    float*         rnorm = (float*)((char*)d_ws + ebf_bytes);
    unsigned char* flags = (unsigned char*)((char*)d_ws + ebf_bytes + rn_bytes);

    hipMemsetAsync(flags, 0, V, stream);
    const int ntok = B * BQ + B * BD;   // 139264
    knrm_mark<<<(ntok + 255) / 256, 256, 0, stream>>>(qtok, dtok, flags);
    knrm_norm<<<(V + 31) / 32, 256, 0, stream>>>(emb, flags, ebf, rnorm, V);
    knrm_main10<<<B, 512, 0, stream>>>(qtok, dtok, ebf, rnorm, mu, sg, dw, dbias, out);
}

// Round 4
// 222.493 us; speedup vs baseline: 1.1073x; 1.0120x over previous
//
#include <hip/hip_runtime.h>

// KNRM round 14: pair-interleaved row layout -> 1 VMEM request per 64-B line.
//  R13 post-mortem: deep prefetch neutral -> not latency-bound. R11/R10
//  comparison -> not byte- or line-bound. Surviving model: main is bound
//  by VMEM REQUEST COUNT (~27 G req/s chip-wide). R11 issues 10 b64
//  gather instrs/row (quad lanes cover 32 B -> every 64-B line hit by TWO
//  instructions). R14 re-permutes the fp8 row at quantization time:
//    fragment(ks,quad) byte = (ks>>1)*64 + quad*16 + (ks&1)*8
//  so ONE b128 per lane fetches fragments ks=2k2,2k2+1 and the 4 quad
//  lanes cover exactly one aligned 64-B line: 5 instrs/row, 1 request per
//  line - half of R11's requests. Fragment VALUES bit-identical to R11
//  (passed, 223.5us); layout-only change. Everything else = R11: fp8 e4m3
//  per-row scale (max->64), rnorm from dequantized values, 320-B rows,
//  double-buffered frags, fused epilogue.

#define B      256
#define BQ     32
#define BD     512
#define EDIM   300
#define ROWB   320   // bytes per fp8 row (300 data + 20 zero pad), 64-B aligned
#define NK     11
#define QSTR   336   // q_buf row stride in BYTES (16-B aligned, odd multiple of 16)

typedef float floatx4 __attribute__((ext_vector_type(4)));
typedef long  longx2  __attribute__((ext_vector_type(2)));

__device__ __forceinline__ float sbc(float x) {   // force into SGPR
    return __uint_as_float(__builtin_amdgcn_readfirstlane(__float_as_uint(x)));
}

// ---------------- Phase 0: mark referenced vocab rows ----------------
__global__ __launch_bounds__(256)
void knrm_mark(const int* __restrict__ qtok, const int* __restrict__ dtok,
               unsigned char* __restrict__ flags)
{
    int i = blockIdx.x * 256 + threadIdx.x;
    const int NQ = B * BQ;              // 8192
    const int ND = B * BD;              // 131072
    if (i < NQ) flags[qtok[i]] = 1;
    else if (i < NQ + ND) flags[dtok[i - NQ]] = 1;
}

// ---------------- Phase 1: normalize / quantize referenced rows ----------------
// 8 lanes/row, 32 rows per 256-thread block. Per-row dynamic scale
// (max|x| -> 64), rnorm from the DEQUANTIZED values. Pair-interleaved
// output layout: group j (elements 8j..8j+7, ks=j>>2, q=j&3) lands at
// uint2 index (j>>3)*8 + (j&3)*2 + ((j>>2)&1)  [byte (ks>>1)*64+q*16+(ks&1)*8].
// Lanes part=0..7 at fixed i cover one full 64-B block -> store coalescing kept.
__global__ __launch_bounds__(256)
void knrm_norm(const float* __restrict__ emb, const unsigned char* __restrict__ flags,
               unsigned char* __restrict__ ebf, float* __restrict__ rnorm, int V)
{
    int r    = blockIdx.x * 32 + (threadIdx.x >> 3);
    int part = threadIdx.x & 7;
    if (r >= V) return;
    if (!flags[r]) return;              // unreferenced: never read by main
    const float4* src = (const float4*)(emb + (size_t)r * EDIM);
    float v[5][8];
    float mx = 0.f;
    #pragma unroll
    for (int i = 0; i < 5; ++i) {
        int j = part + i * 8;               // 8-float group index 0..39
        #pragma unroll
        for (int t = 0; t < 8; ++t) v[i][t] = 0.f;
        if (j < 37) {
            float4 a = src[2 * j];
            float4 c = src[2 * j + 1];
            v[i][0] = a.x; v[i][1] = a.y; v[i][2] = a.z; v[i][3] = a.w;
            v[i][4] = c.x; v[i][5] = c.y; v[i][6] = c.z; v[i][7] = c.w;
        } else if (j == 37) {               // floats 296..299 valid, 300..303 pad
            float4 a = src[74];
            v[i][0] = a.x; v[i][1] = a.y; v[i][2] = a.z; v[i][3] = a.w;
        }                                   // j = 38,39: all pad zeros
        #pragma unroll
        for (int t = 0; t < 8; ++t) mx = fmaxf(mx, fabsf(v[i][t]));
    }
    mx = fmaxf(mx, __shfl_xor(mx, 1));
    mx = fmaxf(mx, __shfl_xor(mx, 2));
    mx = fmaxf(mx, __shfl_xor(mx, 4));
    float s = (mx > 0.f) ? (64.f / mx) : 0.f;   // max -> 64: e4m3 sweet spot

    float ss = 0.f;
    uint2* dst = (uint2*)(ebf + (size_t)r * ROWB);   // 40 x uint2 per row
    #pragma unroll
    for (int i = 0; i < 5; ++i) {
        int j = part + i * 8;
        unsigned int w0 = 0u, w1 = 0u;
        w0 = __builtin_amdgcn_cvt_pk_fp8_f32(v[i][0] * s, v[i][1] * s, w0, false);
        w0 = __builtin_amdgcn_cvt_pk_fp8_f32(v[i][2] * s, v[i][3] * s, w0, true);
        w1 = __builtin_amdgcn_cvt_pk_fp8_f32(v[i][4] * s, v[i][5] * s, w1, false);
        w1 = __builtin_amdgcn_cvt_pk_fp8_f32(v[i][6] * s, v[i][7] * s, w1, true);
        float g;
        g = __builtin_amdgcn_cvt_f32_fp8(w0, 0); ss += g * g;
        g = __builtin_amdgcn_cvt_f32_fp8(w0, 1); ss += g * g;
        g = __builtin_amdgcn_cvt_f32_fp8(w0, 2); ss += g * g;
        g = __builtin_amdgcn_cvt_f32_fp8(w0, 3); ss += g * g;
        g = __builtin_amdgcn_cvt_f32_fp8(w1, 0); ss += g * g;
        g = __builtin_amdgcn_cvt_f32_fp8(w1, 1); ss += g * g;
        g = __builtin_amdgcn_cvt_f32_fp8(w1, 2); ss += g * g;
        g = __builtin_amdgcn_cvt_f32_fp8(w1, 3); ss += g * g;
        uint2 o; o.x = w0; o.y = w1;
        dst[(j >> 3) * 8 + (j & 3) * 2 + ((j >> 2) & 1)] = o;   // pair-interleaved
    }
    ss += __shfl_xor(ss, 1);
    ss += __shfl_xor(ss, 2);
    ss += __shfl_xor(ss, 4);
    if (part == 0) rnorm[r] = 1.f / (sqrtf(ss) + 1e-13f);
}

// ---------------- Phase 2: fused gather + fp8 MFMA + Gaussians + epilogue ----------------
// One b128 per lane per 64-B line: 5 loads/row, quad lanes cover the full line.
__device__ __forceinline__ void load_frags(longx2* bf, const unsigned char* __restrict__ ebf,
                                           int tok, int quad)
{
    const longx2* src = (const longx2*)(ebf + (size_t)tok * ROWB);   // 20 longx2/row
    #pragma unroll
    for (int k2 = 0; k2 < 5; ++k2)
        bf[k2] = src[k2 * 4 + quad];     // byte k2*64 + quad*16
}

__global__ __launch_bounds__(512, 2)
void knrm_main11(const int* __restrict__ qtok, const int* __restrict__ dtok,
                 const unsigned char* __restrict__ ebf, const float* __restrict__ rnorm,
                 const float* __restrict__ mu, const float* __restrict__ sigma,
                 const float* __restrict__ dw, const float* __restrict__ db,
                 float* __restrict__ out)
{
    __shared__ __align__(16) unsigned char q_buf[BQ * QSTR];   // 10752 B
    __shared__ float pkq_s[BQ * NK];
    __shared__ float rqs[BQ];
    __shared__ float red[BQ];

    const int tid  = threadIdx.x;
    const int lane = tid & 63;
    const int wv   = tid >> 6;            // 0..7
    const int b    = blockIdx.x;          // one block per batch
    const int l16  = lane & 15;
    const int quad = lane >> 4;

    for (int i = tid; i < BQ * NK; i += 512) pkq_s[i] = 0.f;
    if (tid < BQ) rqs[tid] = rnorm[qtok[b * BQ + tid]];

    // this wave's d rows: step s -> row s*128 + wv*16 + l16
    const int dbase = b * BD + wv * 16 + l16;
    int   td[4];
    float rd[4], dm[4];
    #pragma unroll
    for (int s = 0; s < 4; ++s) {
        td[s] = dtok[dbase + s * 128];
        rd[s] = rnorm[td[s]];
        dm[s] = (td[s] > 0) ? 1.f : 0.f;
    }

    // stage the 32 q rows once per batch: 16 threads/row, raw byte copy
    // (rows already in the pair-interleaved layout; copy is layout-agnostic)
    {
        int row = tid >> 4, part = tid & 15;
        int tok = qtok[b * BQ + row];
        const uint4* src  = (const uint4*)(ebf + (size_t)tok * ROWB);
        uint4*       qrow = (uint4*)&q_buf[row * QSTR];
        qrow[part] = src[part];
        if (part < 4) qrow[16 + part] = src[16 + part];
    }

    // prefetch step-0 B-fragments while the barrier drains
    longx2 bf0[5], bf1[5];
    load_frags(bf0, ebf, td[0], quad);

    __syncthreads();

    float mur[NK], cfr[NK];
    #pragma unroll
    for (int k = 0; k < NK; ++k) {
        float s = sbc(sigma[k]);
        mur[k] = sbc(mu[k]);
        cfr[k] = -0.5f / (s * s);
    }
    float rqv[8];
    #pragma unroll
    for (int slab = 0; slab < 2; ++slab)
        #pragma unroll
        for (int r = 0; r < 4; ++r)
            rqv[slab * 4 + r] = rqs[slab * 16 + quad * 4 + r];

    const unsigned char* a0 = &q_buf[l16 * QSTR + quad * 16];
    const unsigned char* a1 = a0 + 16 * QSTR;

    float pk[2][4][NK];
    #pragma unroll
    for (int slab = 0; slab < 2; ++slab)
        #pragma unroll
        for (int r = 0; r < 4; ++r)
            #pragma unroll
            for (int k = 0; k < NK; ++k) pk[slab][r][k] = 0.f;

    #pragma unroll
    for (int s = 0; s < 4; ++s) {
        const longx2* bf = (s & 1) ? bf1 : bf0;

        floatx4 acc0 = {0.f, 0.f, 0.f, 0.f};
        floatx4 acc1 = {0.f, 0.f, 0.f, 0.f};
        #pragma unroll
        for (int k2 = 0; k2 < 5; ++k2) {
            longx2 vA0 = *(const longx2*)(a0 + k2 * 64);
            longx2 vA1 = *(const longx2*)(a1 + k2 * 64);
            acc0 = __builtin_amdgcn_mfma_f32_16x16x32_fp8_fp8(vA0.x, bf[k2].x, acc0, 0, 0, 0);
            acc0 = __builtin_amdgcn_mfma_f32_16x16x32_fp8_fp8(vA0.y, bf[k2].y, acc0, 0, 0, 0);
            acc1 = __builtin_amdgcn_mfma_f32_16x16x32_fp8_fp8(vA1.x, bf[k2].x, acc1, 0, 0, 0);
            acc1 = __builtin_amdgcn_mfma_f32_16x16x32_fp8_fp8(vA1.y, bf[k2].y, acc1, 0, 0, 0);
        }

        // issue next step's loads BEFORE the exp tail (they land under it)
        if (s < 3) load_frags((s & 1) ? bf0 : bf1, ebf, td[s + 1], quad);

        #pragma unroll
        for (int slab = 0; slab < 2; ++slab) {
            floatx4 acc = slab ? acc1 : acc0;
            #pragma unroll
            for (int r = 0; r < 4; ++r) {
                float c0 = acc[r] * rqv[slab * 4 + r] * rd[s];
                #pragma unroll
                for (int k = 0; k < NK; ++k) {
                    float d0 = c0 - mur[k];
                    pk[slab][r][k] += dm[s] * __expf(cfr[k] * d0 * d0);
                }
            }
        }
    }

    // ONE cross-lane reduce (sum 16 d-lanes per quad) + LDS combine
    #pragma unroll
    for (int slab = 0; slab < 2; ++slab)
        #pragma unroll
        for (int r = 0; r < 4; ++r)
            #pragma unroll
            for (int k = 0; k < NK; ++k) {
                float v = pk[slab][r][k];
                v += __shfl_xor(v, 1);
                v += __shfl_xor(v, 2);
                v += __shfl_xor(v, 4);
                v += __shfl_xor(v, 8);
                if (l16 == 0)
                    atomicAdd(&pkq_s[(slab * 16 + quad * 4 + r) * NK + k], v);
            }
    __syncthreads();

    // fused epilogue: log/mask/dot -> out[b]
    if (tid < BQ) {
        int tok = qtok[b * BQ + tid];
        float sq = 0.f;
        if (tok > 0) {
            #pragma unroll
            for (int k = 0; k < NK; ++k) {
                float s = fmaxf(pkq_s[tid * NK + k], 1e-10f);
                sq += __logf(s) * 0.01f * dw[k];
            }
        }
        red[tid] = sq;
    }
    __syncthreads();
    if (tid == 0) {
        float s = db[0];
        #pragma unroll 8
        for (int i = 0; i < BQ; ++i) s += red[i];
        out[b] = s;
    }
}

extern "C" void kernel_launch(void* const* d_in, const int* in_sizes, int n_in,
                              void* d_out, int out_size, void* d_ws, size_t ws_size,
                              hipStream_t stream)
{
    const int*   qtok  = (const int*)d_in[0];
    const int*   dtok  = (const int*)d_in[1];
    const float* emb   = (const float*)d_in[2];
    const float* dw    = (const float*)d_in[3];
    const float* dbias = (const float*)d_in[4];
    const float* mu    = (const float*)d_in[5];
    const float* sg    = (const float*)d_in[6];
    float* out = (float*)d_out;

    const int V = in_sizes[2] / EDIM;   // 100000
    const size_t ebf_bytes = (size_t)V * ROWB;       // 32 MB
    const size_t rn_bytes  = (size_t)((V * 4 + 255) & ~255);

    unsigned char* ebf   = (unsigned char*)d_ws;
    float*         rnorm = (float*)((char*)d_ws + ebf_bytes);
    unsigned char* flags = (unsigned char*)((char*)d_ws + ebf_bytes + rn_bytes);

    hipMemsetAsync(flags, 0, V, stream);
    const int ntok = B * BQ + B * BD;   // 139264
    knrm_mark<<<(ntok + 255) / 256, 256, 0, stream>>>(qtok, dtok, flags);
    knrm_norm<<<(V + 31) / 32, 256, 0, stream>>>(emb, flags, ebf, rnorm, V);
    knrm_main11<<<B, 512, 0, stream>>>(qtok, dtok, ebf, rnorm, mu, sg, dw, dbias, out);
}